// Round 1
// baseline (5470.483 us; speedup 1.0000x reference)
//
#include <hip/hip_runtime.h>

// GCN 2-layer: x[N,3] @ W1 -> scatter -> relu -> @ W2 -> scatter -> out[N,2]
// Factorization: out[d] = dinv[d] * ( sum_{s->d} h[s]*dinv[s]  +  h[d]*dinv[d] ) + b
// so we scatter g = h*dinv over real edges only; self-loop term seeds the accumulator.

__global__ void k_init_deg(float* __restrict__ deg, int n) {
    int i = blockIdx.x * blockDim.x + threadIdx.x;
    if (i < n) deg[i] = 1.0f;  // self-loop
}

__global__ void k_count_deg(const int* __restrict__ dst, float* __restrict__ deg, int e) {
    int i = blockIdx.x * blockDim.x + threadIdx.x;
    if (i < e) atomicAdd(&deg[dst[i]], 1.0f);
}

__global__ void k_dinv(float* __restrict__ deg, int n) {
    int i = blockIdx.x * blockDim.x + threadIdx.x;
    if (i < n) deg[i] = rsqrtf(deg[i]);  // deg >= 1 always (self-loops)
}

// h = x @ W1 ; g1 = h * dinv ; acc1 seeded with self-loop g1
__global__ void k_layer1(const float* __restrict__ x, const float* __restrict__ W1,
                         const float* __restrict__ dinv,
                         float* __restrict__ g1, float* __restrict__ acc1, int n) {
    int i = blockIdx.x * blockDim.x + threadIdx.x;
    if (i >= n) return;
    float x0 = x[3 * i + 0], x1 = x[3 * i + 1], x2 = x[3 * i + 2];
    float di = dinv[i];
    float g[8];
#pragma unroll
    for (int j = 0; j < 8; ++j) {
        float h = x0 * W1[j] + x1 * W1[8 + j] + x2 * W1[16 + j];  // W1 is [3][8] row-major
        g[j] = h * di;
    }
    float4 v0 = make_float4(g[0], g[1], g[2], g[3]);
    float4 v1 = make_float4(g[4], g[5], g[6], g[7]);
    float4* gp = (float4*)(g1 + 8ll * i);
    float4* ap = (float4*)(acc1 + 8ll * i);
    gp[0] = v0; gp[1] = v1;
    ap[0] = v0; ap[1] = v1;  // self-loop contribution
}

__global__ void k_scatter1(const int* __restrict__ src, const int* __restrict__ dst,
                           const float* __restrict__ g1, float* __restrict__ acc1, int e) {
    int i = blockIdx.x * blockDim.x + threadIdx.x;
    if (i >= e) return;
    int s = src[i], d = dst[i];
    const float4* gs = (const float4*)(g1 + 8ll * s);
    float4 v0 = gs[0], v1 = gs[1];
    float* ad = acc1 + 8ll * d;
    atomicAdd(ad + 0, v0.x); atomicAdd(ad + 1, v0.y);
    atomicAdd(ad + 2, v0.z); atomicAdd(ad + 3, v0.w);
    atomicAdd(ad + 4, v1.x); atomicAdd(ad + 5, v1.y);
    atomicAdd(ad + 6, v1.z); atomicAdd(ad + 7, v1.w);
}

// o1 = acc1*dinv + b1 ; r = relu(o1) ; h2 = r @ W2 ; g2 = h2*dinv ; acc2(d_out) seeded
__global__ void k_layer2(const float* __restrict__ acc1, const float* __restrict__ dinv,
                         const float* __restrict__ b1, const float* __restrict__ W2,
                         float* __restrict__ g2, float* __restrict__ acc2, int n) {
    int i = blockIdx.x * blockDim.x + threadIdx.x;
    if (i >= n) return;
    float di = dinv[i];
    const float4* ap = (const float4*)(acc1 + 8ll * i);
    float4 a0 = ap[0], a1 = ap[1];
    float r[8] = { a0.x, a0.y, a0.z, a0.w, a1.x, a1.y, a1.z, a1.w };
    float h0 = 0.0f, h1 = 0.0f;
#pragma unroll
    for (int j = 0; j < 8; ++j) {
        float rj = fmaxf(r[j] * di + b1[j], 0.0f);
        h0 += rj * W2[2 * j + 0];  // W2 is [8][2] row-major
        h1 += rj * W2[2 * j + 1];
    }
    float2 g = make_float2(h0 * di, h1 * di);
    *(float2*)(g2 + 2ll * i) = g;
    *(float2*)(acc2 + 2ll * i) = g;  // self-loop contribution
}

__global__ void k_scatter2(const int* __restrict__ src, const int* __restrict__ dst,
                           const float* __restrict__ g2, float* __restrict__ acc2, int e) {
    int i = blockIdx.x * blockDim.x + threadIdx.x;
    if (i >= e) return;
    int s = src[i], d = dst[i];
    float2 v = *(const float2*)(g2 + 2ll * s);
    float* ad = acc2 + 2ll * d;
    atomicAdd(ad + 0, v.x);
    atomicAdd(ad + 1, v.y);
}

__global__ void k_final2(float* __restrict__ out, const float* __restrict__ dinv,
                         const float* __restrict__ b2, int n) {
    int i = blockIdx.x * blockDim.x + threadIdx.x;
    if (i >= n) return;
    float di = dinv[i];
    float2 v = *(float2*)(out + 2ll * i);
    v.x = v.x * di + b2[0];
    v.y = v.y * di + b2[1];
    *(float2*)(out + 2ll * i) = v;
}

extern "C" void kernel_launch(void* const* d_in, const int* in_sizes, int n_in,
                              void* d_out, int out_size, void* d_ws, size_t ws_size,
                              hipStream_t stream) {
    const float* x  = (const float*)d_in[0];
    const int*   ei = (const int*)d_in[1];
    const float* W1 = (const float*)d_in[2];
    const float* b1 = (const float*)d_in[3];
    const float* W2 = (const float*)d_in[4];
    const float* b2 = (const float*)d_in[5];
    float* out = (float*)d_out;

    const int n = in_sizes[0] / 3;   // 1,000,000
    const int e = in_sizes[1] / 2;   // 10,000,000
    const int* src = ei;
    const int* dst = ei + e;

    // workspace layout (floats): dinv[n] | g1[8n] | acc1[8n] | g2[2n]  = 19n floats = 76 MB
    float* ws   = (float*)d_ws;
    float* dinv = ws;
    float* g1   = ws + (size_t)n;
    float* acc1 = g1 + 8 * (size_t)n;
    float* g2   = acc1 + 8 * (size_t)n;

    const int B = 256;
    const int nb_n = (n + B - 1) / B;
    const int nb_e = (e + B - 1) / B;

    k_init_deg <<<nb_n, B, 0, stream>>>(dinv, n);
    k_count_deg<<<nb_e, B, 0, stream>>>(dst, dinv, e);
    k_dinv     <<<nb_n, B, 0, stream>>>(dinv, n);
    k_layer1   <<<nb_n, B, 0, stream>>>(x, W1, dinv, g1, acc1, n);
    k_scatter1 <<<nb_e, B, 0, stream>>>(src, dst, g1, acc1, e);
    k_layer2   <<<nb_n, B, 0, stream>>>(acc1, dinv, b1, W2, g2, out, n);
    k_scatter2 <<<nb_e, B, 0, stream>>>(src, dst, g2, out, e);
    k_final2   <<<nb_n, B, 0, stream>>>(out, dinv, b2, n);
}

// Round 2
// 1670.466 us; speedup vs baseline: 3.2748x; 3.2748x over previous
//
#include <hip/hip_runtime.h>

// 2-layer GCN via CSR build (counting sort by dst) + gather aggregation.
// out1[d] = dinv[d]*(sum_{s->d} x[s]*dinv[s] + x[d]*dinv[d]) @ W1 + b1
// g2[i]   = (relu(out1[i]) @ W2) * dinv[i]
// out[d]  = dinv[d]*(sum_{s->d} g2[s] + g2[d]) + b2
// Zero fp atomics: 10M int atomics for histogram + 10M for placement; both
// layers reuse the same CSR.

#define SCAN_CHUNK 2048  // elements per scan block (256 thr x 8)

__global__ void k_count(const int* __restrict__ dst, int* __restrict__ deg, int e) {
    int i = blockIdx.x * blockDim.x + threadIdx.x;
    if (i < e) atomicAdd(&deg[dst[i]], 1);
}

// per-block sums of deg over chunks of SCAN_CHUNK
__global__ void k_scan_sums(const int* __restrict__ deg, int* __restrict__ bsum, int n) {
    __shared__ int sh[256];
    int t = threadIdx.x;
    int base = blockIdx.x * SCAN_CHUNK;
    int idx = base + t * 8;
    int s = 0;
    if (idx + 7 < n) {
        int4 a = *(const int4*)(deg + idx);
        int4 b = *(const int4*)(deg + idx + 4);
        s = a.x + a.y + a.z + a.w + b.x + b.y + b.z + b.w;
    } else {
        for (int k = 0; k < 8; ++k)
            if (idx + k < n) s += deg[idx + k];
    }
    sh[t] = s;
    __syncthreads();
    for (int off = 1; off < 256; off <<= 1) {
        int v = (t >= off) ? sh[t - off] : 0;
        __syncthreads();
        sh[t] += v;
        __syncthreads();
    }
    if (t == 255) bsum[blockIdx.x] = sh[255];
}

// single-block exclusive scan of up to 1024 block sums (in place)
__global__ void k_scan_top(int* __restrict__ bsum, int nb) {
    __shared__ int sh[1024];
    int t = threadIdx.x;
    int orig = (t < nb) ? bsum[t] : 0;
    sh[t] = orig;
    __syncthreads();
    for (int off = 1; off < 1024; off <<= 1) {
        int v = (t >= off) ? sh[t - off] : 0;
        __syncthreads();
        sh[t] += v;
        __syncthreads();
    }
    if (t < nb) bsum[t] = sh[t] - orig;  // exclusive
}

// cursor[i] = exclusive prefix sum of deg
__global__ void k_scan_out(const int* __restrict__ deg, const int* __restrict__ bsum,
                           int* __restrict__ cursor, int n) {
    __shared__ int sh[256];
    int t = threadIdx.x;
    int base = blockIdx.x * SCAN_CHUNK;
    int idx = base + t * 8;
    int v[8];
    if (idx + 7 < n) {
        int4 a = *(const int4*)(deg + idx);
        int4 b = *(const int4*)(deg + idx + 4);
        v[0] = a.x; v[1] = a.y; v[2] = a.z; v[3] = a.w;
        v[4] = b.x; v[5] = b.y; v[6] = b.z; v[7] = b.w;
    } else {
        for (int k = 0; k < 8; ++k) v[k] = (idx + k < n) ? deg[idx + k] : 0;
    }
    int ex[8];
    int tot = 0;
    for (int k = 0; k < 8; ++k) { ex[k] = tot; tot += v[k]; }
    sh[t] = tot;
    __syncthreads();
    for (int off = 1; off < 256; off <<= 1) {
        int w = (t >= off) ? sh[t - off] : 0;
        __syncthreads();
        sh[t] += w;
        __syncthreads();
    }
    int toff = sh[t] - tot + bsum[blockIdx.x];
    for (int k = 0; k < 8; ++k)
        if (idx + k < n) cursor[idx + k] = toff + ex[k];
}

// dinv + pre-scaled features: xd = {x*dinv, dinv}
__global__ void k_xd(const float* __restrict__ x, const int* __restrict__ deg,
                     float4* __restrict__ xd, int n) {
    int i = blockIdx.x * blockDim.x + threadIdx.x;
    if (i >= n) return;
    float di = rsqrtf((float)deg[i] + 1.0f);  // +1 self-loop
    float x0 = x[3 * i + 0], x1 = x[3 * i + 1], x2 = x[3 * i + 2];
    xd[i] = make_float4(x0 * di, x1 * di, x2 * di, di);
}

__global__ void k_place(const int* __restrict__ src, const int* __restrict__ dst,
                        int* __restrict__ cursor, int* __restrict__ ssrc, int e) {
    int i = blockIdx.x * blockDim.x + threadIdx.x;
    if (i >= e) return;
    int pos = atomicAdd(&cursor[dst[i]], 1);
    ssrc[pos] = src[i];
}

// layer1 aggregate + full node pipeline -> g2
__global__ void k_agg1(const int* __restrict__ deg, const int* __restrict__ cursor,
                       const int* __restrict__ ssrc, const float4* __restrict__ xd,
                       const float* __restrict__ W1, const float* __restrict__ b1,
                       const float* __restrict__ W2, float2* __restrict__ g2, int n) {
    int d = blockIdx.x * blockDim.x + threadIdx.x;
    if (d >= n) return;
    int end = cursor[d];          // after placement: rowptr[d] + deg[d]
    int beg = end - deg[d];
    float4 sd = xd[d];
    float a0 = sd.x, a1 = sd.y, a2 = sd.z;  // self-loop term
    for (int p = beg; p < end; ++p) {
        float4 v = xd[ssrc[p]];
        a0 += v.x; a1 += v.y; a2 += v.z;
    }
    float di = sd.w;
    a0 *= di; a1 *= di; a2 *= di;
    float h0 = 0.0f, h1 = 0.0f;
#pragma unroll
    for (int j = 0; j < 8; ++j) {
        float r = fmaxf(a0 * W1[j] + a1 * W1[8 + j] + a2 * W1[16 + j] + b1[j], 0.0f);
        h0 += r * W2[2 * j + 0];
        h1 += r * W2[2 * j + 1];
    }
    g2[d] = make_float2(h0 * di, h1 * di);
}

// layer2 aggregate -> out
__global__ void k_agg2(const int* __restrict__ deg, const int* __restrict__ cursor,
                       const int* __restrict__ ssrc, const float4* __restrict__ xd,
                       const float2* __restrict__ g2, const float* __restrict__ b2,
                       float2* __restrict__ out, int n) {
    int d = blockIdx.x * blockDim.x + threadIdx.x;
    if (d >= n) return;
    int end = cursor[d];
    int beg = end - deg[d];
    float2 sv = g2[d];
    float s0 = sv.x, s1 = sv.y;
    for (int p = beg; p < end; ++p) {
        float2 v = g2[ssrc[p]];
        s0 += v.x; s1 += v.y;
    }
    float di = xd[d].w;
    out[d] = make_float2(s0 * di + b2[0], s1 * di + b2[1]);
}

extern "C" void kernel_launch(void* const* d_in, const int* in_sizes, int n_in,
                              void* d_out, int out_size, void* d_ws, size_t ws_size,
                              hipStream_t stream) {
    const float* x  = (const float*)d_in[0];
    const int*   ei = (const int*)d_in[1];
    const float* W1 = (const float*)d_in[2];
    const float* b1 = (const float*)d_in[3];
    const float* W2 = (const float*)d_in[4];
    const float* b2 = (const float*)d_in[5];
    float2* out = (float2*)d_out;

    const int n = in_sizes[0] / 3;   // 1,000,000
    const int e = in_sizes[1] / 2;   // 10,000,000
    const int* src = ei;
    const int* dst = ei + e;

    // ws layout (16B-aligned head): xd[n] float4 | g2[n] float2 | deg[n] int |
    //                               cursor[n] int | ssrc[e] int | bsum[1024] int
    char* w = (char*)d_ws;
    float4* xd   = (float4*)w;                  w += (size_t)n * sizeof(float4);
    float2* g2   = (float2*)w;                  w += (size_t)n * sizeof(float2);
    int*    deg  = (int*)w;                     w += (size_t)n * sizeof(int);
    int*    curs = (int*)w;                     w += (size_t)n * sizeof(int);
    int*    ssrc = (int*)w;                     w += (size_t)e * sizeof(int);
    int*    bsum = (int*)w;

    const int Bsz = 256;
    const int nb_n = (n + Bsz - 1) / Bsz;
    const int nb_e = (e + Bsz - 1) / Bsz;
    const int nb_s = (n + SCAN_CHUNK - 1) / SCAN_CHUNK;  // 489 <= 1024

    hipMemsetAsync(deg, 0, (size_t)n * sizeof(int), stream);
    k_count    <<<nb_e, Bsz, 0, stream>>>(dst, deg, e);
    k_scan_sums<<<nb_s, Bsz, 0, stream>>>(deg, bsum, n);
    k_scan_top <<<1, 1024, 0, stream>>>(bsum, nb_s);
    k_scan_out <<<nb_s, Bsz, 0, stream>>>(deg, bsum, curs, n);
    k_xd       <<<nb_n, Bsz, 0, stream>>>(x, deg, xd, n);
    k_place    <<<nb_e, Bsz, 0, stream>>>(src, dst, curs, ssrc, e);
    k_agg1     <<<nb_n, Bsz, 0, stream>>>(deg, curs, ssrc, xd, W1, b1, W2, g2, n);
    k_agg2     <<<nb_n, Bsz, 0, stream>>>(deg, curs, ssrc, xd, g2, b2, out, n);
}

// Round 3
// 888.403 us; speedup vs baseline: 6.1577x; 1.8803x over previous
//
#include <hip/hip_runtime.h>

// 2-layer GCN via bucketed counting sort (4K buckets of 256 dst-nodes) +
// per-bucket LDS aggregation. Zero global fp atomics.
//   xd[i]  = {x[i]*dinv[i], dinv[i]},  dinv = rsqrt(deg+1)
//   g2[i]  = (relu((sum_in xd + xd[i]).xyz * dinv @ W1 + b1) @ W2) * dinv
//   out[d] = (sum_in g2 + g2[d]) * dinv + b2
// Packing assumes n < 2^24 (problem fixed at n = 1e6).

#define BKT_SHIFT 8
#define BKT_SIZE 256
#define MAX_BKT 4096
#define CUR_PAD 16  // ints per cursor (64B line) to avoid per-line atomic serialization

__global__ void k_bhist(const int* __restrict__ dst, int* __restrict__ bcnt,
                        int e, int nbkt) {
    __shared__ int h[MAX_BKT];
    for (int i = threadIdx.x; i < nbkt; i += blockDim.x) h[i] = 0;
    __syncthreads();
    int stride = gridDim.x * blockDim.x;
    for (int i = blockIdx.x * blockDim.x + threadIdx.x; i < e; i += stride)
        atomicAdd(&h[dst[i] >> BKT_SHIFT], 1);
    __syncthreads();
    for (int i = threadIdx.x; i < nbkt; i += blockDim.x) {
        int c = h[i];
        if (c) atomicAdd(&bcnt[i], c);
    }
}

// single-block exclusive scan of bucket counts -> bofs, and init padded cursors
__global__ void k_bscan(const int* __restrict__ bcnt, int* __restrict__ bofs,
                        int* __restrict__ bcur, int nbkt) {
    __shared__ int sh[1024];
    int t = threadIdx.x;
    int base = t * 4;
    int v[4];
    int tot = 0;
    for (int k = 0; k < 4; ++k) {
        v[k] = (base + k < nbkt) ? bcnt[base + k] : 0;
        tot += v[k];
    }
    sh[t] = tot;
    __syncthreads();
    for (int off = 1; off < 1024; off <<= 1) {
        int w = (t >= off) ? sh[t - off] : 0;
        __syncthreads();
        sh[t] += w;
        __syncthreads();
    }
    int run = sh[t] - tot;
    for (int k = 0; k < 4; ++k) {
        if (base + k < nbkt) {
            bofs[base + k] = run;
            bcur[(base + k) * CUR_PAD] = run;
        }
        run += v[k];
    }
}

__global__ void k_bplace(const int* __restrict__ src, const int* __restrict__ dst,
                         int* __restrict__ bcur, unsigned* __restrict__ esort, int e) {
    int i = blockIdx.x * blockDim.x + threadIdx.x;
    if (i >= e) return;
    int d = dst[i];
    int pos = atomicAdd(&bcur[(d >> BKT_SHIFT) * CUR_PAD], 1);
    esort[pos] = ((unsigned)(d & (BKT_SIZE - 1)) << 24) | (unsigned)src[i];
}

// per-bucket: LDS degree histogram -> xd = {x*dinv, dinv}
__global__ void k_c1(const unsigned* __restrict__ esort, const int* __restrict__ bofs,
                     const int* __restrict__ bcnt, const float* __restrict__ x,
                     float4* __restrict__ xd, int n) {
    __shared__ int degs[BKT_SIZE];
    int b = blockIdx.x, t = threadIdx.x;
    degs[t] = 0;
    __syncthreads();
    int beg = bofs[b], end = beg + bcnt[b];
    for (int p = beg + t; p < end; p += BKT_SIZE)
        atomicAdd(&degs[esort[p] >> 24], 1);
    __syncthreads();
    int node = b * BKT_SIZE + t;
    if (node < n) {
        float di = rsqrtf((float)degs[t] + 1.0f);  // +1 self-loop
        float x0 = x[3 * node], x1 = x[3 * node + 1], x2 = x[3 * node + 2];
        xd[node] = make_float4(x0 * di, x1 * di, x2 * di, di);
    }
}

// per-bucket layer-1 aggregate + fused node pipeline -> g2
__global__ void k_c2(const unsigned* __restrict__ esort, const int* __restrict__ bofs,
                     const int* __restrict__ bcnt, const float4* __restrict__ xd,
                     const float* __restrict__ W1, const float* __restrict__ b1,
                     const float* __restrict__ W2, float2* __restrict__ g2, int n) {
    __shared__ float acc[BKT_SIZE][4];
    int b = blockIdx.x, t = threadIdx.x;
    acc[t][0] = 0.0f; acc[t][1] = 0.0f; acc[t][2] = 0.0f;
    __syncthreads();
    int beg = bofs[b], end = beg + bcnt[b];
    for (int p = beg + t; p < end; p += BKT_SIZE) {
        unsigned v = esort[p];
        float4 s = xd[v & 0xFFFFFFu];
        int dl = v >> 24;
        atomicAdd(&acc[dl][0], s.x);
        atomicAdd(&acc[dl][1], s.y);
        atomicAdd(&acc[dl][2], s.z);
    }
    __syncthreads();
    int node = b * BKT_SIZE + t;
    if (node >= n) return;
    float4 sd = xd[node];
    float di = sd.w;
    float a0 = (acc[t][0] + sd.x) * di;
    float a1 = (acc[t][1] + sd.y) * di;
    float a2 = (acc[t][2] + sd.z) * di;
    float h0 = 0.0f, h1 = 0.0f;
#pragma unroll
    for (int j = 0; j < 8; ++j) {
        float r = fmaxf(a0 * W1[j] + a1 * W1[8 + j] + a2 * W1[16 + j] + b1[j], 0.0f);
        h0 += r * W2[2 * j + 0];
        h1 += r * W2[2 * j + 1];
    }
    g2[node] = make_float2(h0 * di, h1 * di);
}

// per-bucket layer-2 aggregate -> out
__global__ void k_c3(const unsigned* __restrict__ esort, const int* __restrict__ bofs,
                     const int* __restrict__ bcnt, const float4* __restrict__ xd,
                     const float2* __restrict__ g2, const float* __restrict__ b2,
                     float2* __restrict__ out, int n) {
    __shared__ float acc[BKT_SIZE][2];
    int b = blockIdx.x, t = threadIdx.x;
    acc[t][0] = 0.0f; acc[t][1] = 0.0f;
    __syncthreads();
    int beg = bofs[b], end = beg + bcnt[b];
    for (int p = beg + t; p < end; p += BKT_SIZE) {
        unsigned v = esort[p];
        float2 s = g2[v & 0xFFFFFFu];
        int dl = v >> 24;
        atomicAdd(&acc[dl][0], s.x);
        atomicAdd(&acc[dl][1], s.y);
    }
    __syncthreads();
    int node = b * BKT_SIZE + t;
    if (node >= n) return;
    float2 sv = g2[node];
    float di = xd[node].w;
    out[node] = make_float2((acc[t][0] + sv.x) * di + b2[0],
                            (acc[t][1] + sv.y) * di + b2[1]);
}

extern "C" void kernel_launch(void* const* d_in, const int* in_sizes, int n_in,
                              void* d_out, int out_size, void* d_ws, size_t ws_size,
                              hipStream_t stream) {
    const float* x  = (const float*)d_in[0];
    const int*   ei = (const int*)d_in[1];
    const float* W1 = (const float*)d_in[2];
    const float* b1 = (const float*)d_in[3];
    const float* W2 = (const float*)d_in[4];
    const float* b2 = (const float*)d_in[5];
    float2* out = (float2*)d_out;

    const int n = in_sizes[0] / 3;   // 1,000,000
    const int e = in_sizes[1] / 2;   // 10,000,000
    const int* src = ei;
    const int* dst = ei + e;
    const int nbkt = (n + BKT_SIZE - 1) >> BKT_SHIFT;  // 3907 <= 4096

    // ws: xd float4[n] | g2 float2[n] | esort u32[e] | bcnt[4096] | bofs[4096] | bcur[4096*16]
    char* w = (char*)d_ws;
    float4*   xd    = (float4*)w;    w += (size_t)n * sizeof(float4);
    float2*   g2    = (float2*)w;    w += (size_t)n * sizeof(float2);
    unsigned* esort = (unsigned*)w;  w += (size_t)e * sizeof(unsigned);
    int*      bcnt  = (int*)w;       w += (size_t)MAX_BKT * sizeof(int);
    int*      bofs  = (int*)w;       w += (size_t)MAX_BKT * sizeof(int);
    int*      bcur  = (int*)w;

    const int B = 256;
    const int nb_e = (e + B - 1) / B;

    hipMemsetAsync(bcnt, 0, (size_t)nbkt * sizeof(int), stream);
    k_bhist <<<512, B, 0, stream>>>(dst, bcnt, e, nbkt);
    k_bscan <<<1, 1024, 0, stream>>>(bcnt, bofs, bcur, nbkt);
    k_bplace<<<nb_e, B, 0, stream>>>(src, dst, bcur, esort, e);
    k_c1    <<<nbkt, B, 0, stream>>>(esort, bofs, bcnt, x, xd, n);
    k_c2    <<<nbkt, B, 0, stream>>>(esort, bofs, bcnt, xd, W1, b1, W2, g2, n);
    k_c3    <<<nbkt, B, 0, stream>>>(esort, bofs, bcnt, xd, g2, b2, out, n);
}

// Round 4
// 443.840 us; speedup vs baseline: 12.3254x; 2.0016x over previous
//
#include <hip/hip_runtime.h>

// 2-layer GCN. Counting sort by dst via block-local multisplit (coalesced run
// writes, ~600K global atomics total), then per-4096-node-bucket aggregation
// in LDS. Zero global fp atomics.
//   xd[i]  = {x[i]*dinv[i], dinv[i]},  dinv = rsqrt(deg+1)
//   g2[i]  = (relu(((sum_in xd) + xd[i]).xyz * dinv @ W1 + b1) @ W2) * dinv
//   out[d] = ((sum_in g2) + g2[d]) * dinv + b2
// Edge packed as (dst&4095)<<20 | src  (n = 1e6 < 2^20).

#define BSH 12
#define BKT 4096
#define NBKT_MAX 256
#define TILE 4096  // edges per multisplit tile (256 thr x 16)

__global__ void k_hist(const int* __restrict__ dst, int* __restrict__ bcnt,
                       int e, int nbkt) {
    __shared__ int h[NBKT_MAX];
    int t = threadIdx.x;
    h[t] = 0;
    __syncthreads();
    int stride = gridDim.x * blockDim.x;
    for (int i = blockIdx.x * blockDim.x + t; i < e; i += stride)
        atomicAdd(&h[dst[i] >> BSH], 1);
    __syncthreads();
    if (t < nbkt && h[t]) atomicAdd(&bcnt[t], h[t]);
}

// single 256-thread block: exclusive scan of bucket counts -> bofs, bcur
__global__ void k_scan(const int* __restrict__ bcnt, int* __restrict__ bofs,
                       int* __restrict__ bcur, int nbkt) {
    __shared__ int sh[256];
    int t = threadIdx.x;
    int v = (t < nbkt) ? bcnt[t] : 0;
    sh[t] = v;
    __syncthreads();
    for (int off = 1; off < 256; off <<= 1) {
        int w = (t >= off) ? sh[t - off] : 0;
        __syncthreads();
        sh[t] += w;
        __syncthreads();
    }
    if (t < nbkt) {
        int ex = sh[t] - v;
        bofs[t] = ex;
        bcur[t] = ex;
    }
}

__global__ void k_msplit(const int* __restrict__ src, const int* __restrict__ dst,
                         int* __restrict__ bcur, unsigned* __restrict__ esort,
                         int e, int nbkt) {
    __shared__ unsigned stage[TILE];
    __shared__ unsigned char bid[TILE];
    __shared__ int h[NBKT_MAX];
    __shared__ int lscan[NBKT_MAX];
    __shared__ int baseadj[NBKT_MAX];
    int t = threadIdx.x;
    int base = blockIdx.x * TILE;
    int cnt = min(TILE, e - base);
    h[t] = 0;
    __syncthreads();

    unsigned val[16];
    int bk[16], rnk[16];
#pragma unroll
    for (int k = 0; k < 16; ++k) {
        int i = base + k * 256 + t;
        bk[k] = -1;
        if (i < e) {
            int d = dst[i], s = src[i];
            bk[k] = d >> BSH;
            val[k] = ((unsigned)(d & (BKT - 1)) << 20) | (unsigned)s;
            rnk[k] = atomicAdd(&h[bk[k]], 1);
        }
    }
    __syncthreads();
    // exclusive scan of h (256 wide) + reserve global runs
    int c = h[t];
    __syncthreads();
    // reuse h as inclusive scan buffer via lscan to keep counts
    lscan[t] = c;
    __syncthreads();
    for (int off = 1; off < 256; off <<= 1) {
        int w = (t >= off) ? lscan[t - off] : 0;
        __syncthreads();
        lscan[t] += w;
        __syncthreads();
    }
    int ex = lscan[t] - c;
    __syncthreads();
    lscan[t] = ex;
    if (c > 0) baseadj[t] = atomicAdd(&bcur[t], c) - ex;
    __syncthreads();

#pragma unroll
    for (int k = 0; k < 16; ++k) {
        if (bk[k] >= 0) {
            int idx = lscan[bk[k]] + rnk[k];
            stage[idx] = val[k];
            bid[idx] = (unsigned char)bk[k];
        }
    }
    __syncthreads();
#pragma unroll
    for (int k = 0; k < 16; ++k) {
        int j = k * 256 + t;
        if (j < cnt) esort[baseadj[bid[j]] + j] = stage[j];
    }
}

// per-bucket: degree from sorted edges -> xd = {x*dinv, dinv}
__global__ void k_deg_xd(const unsigned* __restrict__ esort, const int* __restrict__ bofs,
                         const int* __restrict__ bcnt, const float* __restrict__ x,
                         float4* __restrict__ xd, int n) {
    __shared__ int deg[BKT];
    int b = blockIdx.x, t = threadIdx.x;
#pragma unroll
    for (int k = 0; k < BKT / 256; ++k) deg[k * 256 + t] = 0;
    __syncthreads();
    int beg = bofs[b], end = beg + bcnt[b];
    for (int p = beg + t; p < end; p += 256)
        atomicAdd(&deg[esort[p] >> 20], 1);
    __syncthreads();
#pragma unroll
    for (int k = 0; k < BKT / 256; ++k) {
        int dl = k * 256 + t;
        int node = b * BKT + dl;
        if (node < n) {
            float di = rsqrtf((float)deg[dl] + 1.0f);
            float x0 = x[3 * node], x1 = x[3 * node + 1], x2 = x[3 * node + 2];
            xd[node] = make_float4(x0 * di, x1 * di, x2 * di, di);
        }
    }
}

// per-bucket layer-1 aggregate + fused node pipeline -> g2
__global__ void k_l1(const unsigned* __restrict__ esort, const int* __restrict__ bofs,
                     const int* __restrict__ bcnt, const float4* __restrict__ xd,
                     const float* __restrict__ W1, const float* __restrict__ b1,
                     const float* __restrict__ W2, float2* __restrict__ g2, int n) {
    __shared__ float acc[BKT * 3];  // 48 KB
    int b = blockIdx.x, t = threadIdx.x;
#pragma unroll
    for (int k = 0; k < BKT * 3 / 256; ++k) acc[k * 256 + t] = 0.0f;
    __syncthreads();
    int beg = bofs[b], end = beg + bcnt[b];
    for (int p = beg + t; p < end; p += 256) {
        unsigned v = esort[p];
        float4 s = xd[v & 0xFFFFFu];
        int dl = v >> 20;
        atomicAdd(&acc[dl * 3 + 0], s.x);
        atomicAdd(&acc[dl * 3 + 1], s.y);
        atomicAdd(&acc[dl * 3 + 2], s.z);
    }
    __syncthreads();
#pragma unroll
    for (int k = 0; k < BKT / 256; ++k) {
        int dl = k * 256 + t;
        int node = b * BKT + dl;
        if (node >= n) continue;
        float4 sd = xd[node];
        float di = sd.w;
        float a0 = (acc[dl * 3 + 0] + sd.x) * di;
        float a1 = (acc[dl * 3 + 1] + sd.y) * di;
        float a2 = (acc[dl * 3 + 2] + sd.z) * di;
        float h0 = 0.0f, h1 = 0.0f;
#pragma unroll
        for (int j = 0; j < 8; ++j) {
            float r = fmaxf(a0 * W1[j] + a1 * W1[8 + j] + a2 * W1[16 + j] + b1[j], 0.0f);
            h0 += r * W2[2 * j + 0];
            h1 += r * W2[2 * j + 1];
        }
        g2[node] = make_float2(h0 * di, h1 * di);
    }
}

// per-bucket layer-2 aggregate -> out
__global__ void k_l2(const unsigned* __restrict__ esort, const int* __restrict__ bofs,
                     const int* __restrict__ bcnt, const float4* __restrict__ xd,
                     const float2* __restrict__ g2, const float* __restrict__ b2,
                     float2* __restrict__ out, int n) {
    __shared__ float acc[BKT * 2];  // 32 KB
    int b = blockIdx.x, t = threadIdx.x;
#pragma unroll
    for (int k = 0; k < BKT * 2 / 256; ++k) acc[k * 256 + t] = 0.0f;
    __syncthreads();
    int beg = bofs[b], end = beg + bcnt[b];
    for (int p = beg + t; p < end; p += 256) {
        unsigned v = esort[p];
        float2 s = g2[v & 0xFFFFFu];
        int dl = v >> 20;
        atomicAdd(&acc[dl * 2 + 0], s.x);
        atomicAdd(&acc[dl * 2 + 1], s.y);
    }
    __syncthreads();
#pragma unroll
    for (int k = 0; k < BKT / 256; ++k) {
        int dl = k * 256 + t;
        int node = b * BKT + dl;
        if (node >= n) continue;
        float2 sv = g2[node];
        float di = xd[node].w;
        out[node] = make_float2((acc[dl * 2 + 0] + sv.x) * di + b2[0],
                                (acc[dl * 2 + 1] + sv.y) * di + b2[1]);
    }
}

extern "C" void kernel_launch(void* const* d_in, const int* in_sizes, int n_in,
                              void* d_out, int out_size, void* d_ws, size_t ws_size,
                              hipStream_t stream) {
    const float* x  = (const float*)d_in[0];
    const int*   ei = (const int*)d_in[1];
    const float* W1 = (const float*)d_in[2];
    const float* b1 = (const float*)d_in[3];
    const float* W2 = (const float*)d_in[4];
    const float* b2 = (const float*)d_in[5];
    float2* out = (float2*)d_out;

    const int n = in_sizes[0] / 3;   // 1,000,000
    const int e = in_sizes[1] / 2;   // 10,000,000
    const int* src = ei;
    const int* dst = ei + e;
    const int nbkt = (n + BKT - 1) >> BSH;  // 245

    // ws: xd float4[n] | g2 float2[n] | esort u32[e] | bcnt | bofs | bcur
    char* w = (char*)d_ws;
    float4*   xd    = (float4*)w;    w += (size_t)n * sizeof(float4);
    float2*   g2    = (float2*)w;    w += (size_t)n * sizeof(float2);
    unsigned* esort = (unsigned*)w;  w += (size_t)e * sizeof(unsigned);
    int*      bcnt  = (int*)w;       w += (size_t)NBKT_MAX * sizeof(int);
    int*      bofs  = (int*)w;       w += (size_t)NBKT_MAX * sizeof(int);
    int*      bcur  = (int*)w;

    const int B = 256;
    const int nb_ms = (e + TILE - 1) / TILE;  // 2442

    hipMemsetAsync(bcnt, 0, (size_t)NBKT_MAX * sizeof(int), stream);
    k_hist  <<<512, B, 0, stream>>>(dst, bcnt, e, nbkt);
    k_scan  <<<1, B, 0, stream>>>(bcnt, bofs, bcur, nbkt);
    k_msplit<<<nb_ms, B, 0, stream>>>(src, dst, bcur, esort, e, nbkt);
    k_deg_xd<<<nbkt, B, 0, stream>>>(esort, bofs, bcnt, x, xd, n);
    k_l1    <<<nbkt, B, 0, stream>>>(esort, bofs, bcnt, xd, W1, b1, W2, g2, n);
    k_l2    <<<nbkt, B, 0, stream>>>(esort, bofs, bcnt, xd, g2, b2, out, n);
}